// Round 11
// baseline (327.668 us; speedup 1.0000x reference)
//
#include <hip/hip_runtime.h>

#define BATCH 32
#define TT 8
#define VOCAB 2048
#define EMB 256
#define NG 8192          // 4*VOCAB
#define LAT 128
#define KTOT 2304        // EMB + VOCAB
#define NKT 72           // K-tiles of 32
#define NNT 512          // N-tiles of 16
#define NJT 128          // j-tiles of 16

#define WSCALE 4096.0f
#define ASCALE 16.0f
#define DQ (1.0f/65536.0f)   // exact 1/(WSCALE*ASCALE)

typedef float f32x4 __attribute__((ext_vector_type(4)));

// ws layout (float offsets)
#define H_OFF   0
#define C_OFF   (H_OFF + BATCH*VOCAB)
#define ZAC_OFF (C_OFF + BATCH*VOCAB)
#define SAC_OFF (ZAC_OFF + 7*32)
#define EAC_OFF (SAC_OFF + 7*32)
#define AHB_OFF (EAC_OFF + 7*32)      // uchar region: 2 buffers x 32*2304 B
#define AHB_SZF (2*BATCH*KTOT/4)      // 36864 floats
#define BP_OFF  (AHB_OFF + AHB_SZF)   // ull region: 512*72*64 entries (~18.9MB)

__device__ __forceinline__ float sigmoidf_(float x){ return 1.f/(1.f+__expf(-x)); }
__device__ __forceinline__ float tanhf_(float x){
  x = fminf(fmaxf(x, -10.f), 10.f);
  float e = __expf(2.f*x);
  return (e-1.f)/(e+1.f);
}
// float -> OCP e4m3fn, RNE, saturate 448
__device__ __forceinline__ unsigned char f2e4m3(float f){
  unsigned int u = __float_as_uint(f);
  unsigned char sign = (unsigned char)((u >> 24) & 0x80);
  float a = fabsf(f);
  if (a >= 464.f) return sign | 0x7E;
  if (a < 0.015625f){
    float q = rintf(a * 512.f);
    if (q >= 8.f) return sign | 0x08;
    return sign | (unsigned char)q;
  }
  int e;
  frexpf(a, &e);
  int E = e - 1;
  float q = rintf(ldexpf(a, 3 - E));
  int qi = (int)q;
  if (qi == 16){ qi = 8; E += 1; }
  if (E > 8) return sign | 0x7E;
  if (E == 8 && qi > 14) qi = 14;
  return sign | (unsigned char)(((E + 7) << 3) | (qi - 8));
}

// Pack W -> fp8 B-fragments via coalesced read + LDS transpose; fused init.
// Grid (128 n-groups of 64, 72 k-tiles). Bp[nt][kt][lane][8k].
__global__ __launch_bounds__(256) void k_pack(
    const int* __restrict__ tok, const float* __restrict__ E,
    const float* __restrict__ Wi, const float* __restrict__ Wh,
    unsigned long long* __restrict__ Bp, float* __restrict__ h, float* __restrict__ c,
    unsigned char* __restrict__ Ahb1, float* __restrict__ Zac, float* __restrict__ Sac,
    float* __restrict__ out){
  const int tid = threadIdx.x;
  const int nb = blockIdx.x;            // 0..127
  const int kt = blockIdx.y;            // 0..71
  __shared__ unsigned char lds[32][64];
  {
    const int kl = tid >> 3;            // 0..31
    const int n0 = (tid & 7) * 8;
    const int k  = kt*32 + kl;
    const float* W = (k < EMB) ? (Wi + (size_t)k*NG) : (Wh + (size_t)(k-EMB)*NG);
    const float4 f0 = *(const float4*)(W + nb*64 + n0);
    const float4 f1 = *(const float4*)(W + nb*64 + n0 + 4);
    unsigned long long pk = 0ull;
    pk |= (unsigned long long)f2e4m3(f0.x*WSCALE);
    pk |= (unsigned long long)f2e4m3(f0.y*WSCALE) << 8;
    pk |= (unsigned long long)f2e4m3(f0.z*WSCALE) << 16;
    pk |= (unsigned long long)f2e4m3(f0.w*WSCALE) << 24;
    pk |= (unsigned long long)f2e4m3(f1.x*WSCALE) << 32;
    pk |= (unsigned long long)f2e4m3(f1.y*WSCALE) << 40;
    pk |= (unsigned long long)f2e4m3(f1.z*WSCALE) << 48;
    pk |= (unsigned long long)f2e4m3(f1.w*WSCALE) << 56;
    *(unsigned long long*)&lds[kl][n0] = pk;
  }
  __syncthreads();
  {
    const int ntl = tid >> 6, lane = tid & 63;
    const int kgrp = lane >> 4, n16 = lane & 15;
    unsigned long long pk = 0ull;
    #pragma unroll
    for (int p=0;p<8;p++)
      pk |= ((unsigned long long)lds[kgrp*8 + p][ntl*16 + n16]) << (8*p);
    Bp[((size_t)(nb*4 + ntl)*NKT + kt)*64 + lane] = pk;
  }
  // fused init (flat index over 9216*256 = 2.36M threads)
  const int i = (kt*128 + nb)*256 + tid;
  if (i < BATCH*VOCAB){ h[i] = 0.f; c[i] = 0.f; }
  if (i < BATCH*KTOT){
    int b = i / KTOT, k = i % KTOT;
    Ahb1[i] = (k < EMB) ? f2e4m3(ASCALE*E[(size_t)tok[b*TT]*EMB + k]) : (unsigned char)0;
  }
  if (i < BATCH*LAT)
    out[(size_t)((i>>7)*TT + 0)*LAT + (i&(LAT-1))] = 0.f;  // t=0: z=0 exactly
  if (i < 7*32){ Zac[i] = 0.f; Sac[i] = 0.f; }
}

// One LSTM step, ONE kernel: 128 blocks (j-tiles) x 512 thr.
// 8 waves = (gate 0..3) x (batch-half 0..1); each wave full-K M=16xN=16 fp8 MFMA
// with 8-deep double-buffered prefetch. Gates -> LDS -> fused cell -> h,c,
// fp8 h into AhbW (double buffer => no read/write race), softmax stats via
// atomics. Block 0 finalizes the PREVIOUS step's output (t>=2).
__global__ __launch_bounds__(512) void k_step(
    const int* __restrict__ tok, const float* __restrict__ E,
    const float* __restrict__ bias, float* __restrict__ out,
    float* __restrict__ h, float* __restrict__ c,
    float* __restrict__ Zac, float* __restrict__ Sac, float* __restrict__ Eac,
    const unsigned char* __restrict__ AhbR, unsigned char* __restrict__ AhbW,
    const unsigned long long* __restrict__ Bp, int t){
  const int tid = threadIdx.x;
  const int jt = blockIdx.x;                 // 0..127
  const int w = tid >> 6, lane = tid & 63;
  const int g = w & 3, mh = w >> 2;
  const int quad = lane >> 4, col = lane & 15;
  const int slot = t - 1;

  __shared__ float gsh[4][BATCH][16];
  __shared__ float vsh[BATCH];

  if (jt == 0 && t >= 2){                    // block-uniform
    if (tid < BATCH){
      float Z = Zac[(slot-1)*32 + tid], S = Sac[(slot-1)*32 + tid];
      float Ej = Eac[(slot-1)*32 + tid];
      vsh[tid] = (3.f*S + 1.5f*Ej)/Z;
    }
    __syncthreads();
    for (int i=tid; i<BATCH*LAT; i+=512)
      out[(size_t)((i>>7)*TT + (t-1))*LAT + (i&(LAT-1))] = vsh[i>>7];
  }

  // ---- full-K MFMA chain ----
  const int nt = g*NJT + jt;
  const long* __restrict__ AhV = (const long*)AhbR;     // row = 288 x 8B
  const long* __restrict__ BpV = (const long*)Bp;
  const int abase = (mh*16 + col)*(KTOT/8);
  const size_t bbase = (size_t)nt*NKT*64 + lane;

  long bb[2][8], aa[2][8];
  #pragma unroll
  for (int i=0;i<8;i++){
    bb[0][i] = BpV[bbase + (size_t)i*64];
    aa[0][i] = AhV[abase + i*4 + quad];
  }
  f32x4 acc = {0,0,0,0};
  #pragma unroll
  for (int ch=0; ch<9; ch++){
    const int cur = ch & 1, nxt = cur ^ 1;
    if (ch < 8){
      #pragma unroll
      for (int i=0;i<8;i++){
        const int kt2 = (ch+1)*8 + i;
        bb[nxt][i] = BpV[bbase + (size_t)kt2*64];
        aa[nxt][i] = AhV[abase + kt2*4 + quad];
      }
    }
    #pragma unroll
    for (int i=0;i<8;i++)
      acc = __builtin_amdgcn_mfma_f32_16x16x32_fp8_fp8(aa[cur][i], bb[cur][i], acc, 0,0,0);
  }
  // C-layout: row(b_local) = quad*4+r, col(j_local) = col
  const int brow = mh*16 + quad*4;
  #pragma unroll
  for (int r=0;r<4;r++)
    gsh[g][brow + r][col] = acc[r];
  __syncthreads();

  // ---- fused cell: thread = (b, jj) of 32x16 ----
  const int b = tid >> 4, jj = tid & 15;
  const int j = jt*16 + jj;
  float ip = gsh[0][b][jj]*DQ + bias[j];
  float fp = gsh[1][b][jj]*DQ + bias[j + VOCAB];
  float gg = gsh[2][b][jj]*DQ + bias[j + 2*VOCAB];
  float op = gsh[3][b][jj]*DQ + bias[j + 3*VOCAB];
  float cold = c[b*VOCAB + j];
  float cn = sigmoidf_(fp)*cold + sigmoidf_(ip)*tanhf_(gg);
  float hn = sigmoidf_(op)*tanhf_(cn);
  const bool upd = tok[b*TT + (t-1)] != 0;
  float hf = upd ? hn : h[b*VOCAB + j];
  float cf = upd ? cn : cold;
  h[b*VOCAB + j] = hf;
  c[b*VOCAB + j] = cf;
  AhbW[b*KTOT + EMB + j] = f2e4m3(ASCALE*hf);
  const int sj = tok[b*TT + t];
  float e = __expf(hf);                      // h in (-1,1): no max-pass
  if (j == sj) Eac[slot*32 + b] = e;         // unique writer
  float z = e, s = (j < sj) ? e : 0.f;
  #pragma unroll
  for (int m=1; m<16; m<<=1){ z += __shfl_xor(z, m); s += __shfl_xor(s, m); }
  if (jj == 0){
    atomicAdd(&Zac[slot*32 + b], z);
    atomicAdd(&Sac[slot*32 + b], s);
  }
  if (jt < BATCH && t < TT-1 && tid < EMB)   // stage next step's x-row (b = jt)
    AhbW[jt*KTOT + tid] = f2e4m3(ASCALE*E[(size_t)tok[jt*TT + t]*EMB + tid]);
}

// Final output (t = TT-1), slot 6.
__global__ __launch_bounds__(256) void k_out(
    const float* __restrict__ Zac, const float* __restrict__ Sac,
    const float* __restrict__ Eac, float* __restrict__ out){
  const int tid = threadIdx.x;
  __shared__ float vsh[BATCH];
  if (tid < BATCH)
    vsh[tid] = (3.f*Sac[6*32+tid] + 1.5f*Eac[6*32+tid])/Zac[6*32+tid];
  __syncthreads();
  for (int i=tid; i<BATCH*LAT; i+=256)
    out[(size_t)((i>>7)*TT + (TT-1))*LAT + (i&(LAT-1))] = vsh[i>>7];
}

extern "C" void kernel_launch(void* const* d_in, const int* in_sizes, int n_in,
                              void* d_out, int out_size, void* d_ws, size_t ws_size,
                              hipStream_t stream){
  const int*   tok  = (const int*)d_in[0];
  const float* E    = (const float*)d_in[1];
  const float* Wi   = (const float*)d_in[2];
  const float* Wh   = (const float*)d_in[3];
  const float* bias = (const float*)d_in[4];
  float* out = (float*)d_out;
  float* ws  = (float*)d_ws;
  float* h   = ws + H_OFF;
  float* c   = ws + C_OFF;
  float* Zac = ws + ZAC_OFF;
  float* Sac = ws + SAC_OFF;
  float* Eac = ws + EAC_OFF;
  unsigned char* Ahb = (unsigned char*)(ws + AHB_OFF);   // 2 buffers x 73728 B
  unsigned long long* Bp = (unsigned long long*)(ws + BP_OFF);

  k_pack<<<dim3(128, NKT), 256, 0, stream>>>(tok, E, Wi, Wh, Bp, h, c,
                                             Ahb + BATCH*KTOT, Zac, Sac, out);
  for (int t = 1; t < TT; t++){
    unsigned char* AhbR = Ahb + (t & 1)*BATCH*KTOT;
    unsigned char* AhbW = Ahb + ((t & 1) ^ 1)*BATCH*KTOT;
    k_step<<<NJT, 512, 0, stream>>>(tok, E, bias, out, h, c, Zac, Sac, Eac,
                                    AhbR, AhbW, Bp, t);
  }
  k_out<<<1, 256, 0, stream>>>(Zac, Sac, Eac, out);
}

// Round 12
// 198.890 us; speedup vs baseline: 1.6475x; 1.6475x over previous
//
#include <hip/hip_runtime.h>

#define BATCH 32
#define TT 8
#define VOCAB 2048
#define EMB 256
#define NG 8192          // 4*VOCAB
#define LAT 128
#define KTOT 2304        // EMB + VOCAB
#define NKT 72           // K-tiles of 32
#define NNT 512          // N-tiles of 16
#define NJT 128          // j-tiles of 16

#define WSCALE 4096.0f
#define ASCALE 16.0f
#define DQ (1.0f/65536.0f)   // exact 1/(WSCALE*ASCALE)

typedef float f32x4 __attribute__((ext_vector_type(4)));

// ws layout (float offsets)
#define H_OFF   0
#define C_OFF   (H_OFF + BATCH*VOCAB)        // 65536
#define ZAC_OFF (C_OFF + BATCH*VOCAB)        // 131072
#define SAC_OFF (ZAC_OFF + 7*32)
#define EAC_OFF (SAC_OFF + 7*32)
#define AHB_OFF (EAC_OFF + 7*32)             // uchar region: 2 x 32*2304 B (16B-aligned)
#define AHB_SZF (2*BATCH*KTOT/4)             // 36864 floats
#define BP_OFF  (AHB_OFF + AHB_SZF)          // ull region: 512*72*64 (~18.9MB)

__device__ __forceinline__ float sigmoidf_(float x){ return 1.f/(1.f+__expf(-x)); }
__device__ __forceinline__ float tanhf_(float x){
  x = fminf(fmaxf(x, -10.f), 10.f);
  float e = __expf(2.f*x);
  return (e-1.f)/(e+1.f);
}
// float -> OCP e4m3fn, RNE, saturate 448
__device__ __forceinline__ unsigned char f2e4m3(float f){
  unsigned int u = __float_as_uint(f);
  unsigned char sign = (unsigned char)((u >> 24) & 0x80);
  float a = fabsf(f);
  if (a >= 464.f) return sign | 0x7E;
  if (a < 0.015625f){
    float q = rintf(a * 512.f);
    if (q >= 8.f) return sign | 0x08;
    return sign | (unsigned char)q;
  }
  int e;
  frexpf(a, &e);
  int E = e - 1;
  float q = rintf(ldexpf(a, 3 - E));
  int qi = (int)q;
  if (qi == 16){ qi = 8; E += 1; }
  if (E > 8) return sign | 0x7E;
  if (E == 8 && qi > 14) qi = 14;
  return sign | (unsigned char)(((E + 7) << 3) | (qi - 8));
}

// Pack W -> fp8 B-fragments via coalesced read + LDS transpose; fused init.
// Grid (128 n-groups of 64, 72 k-tiles). Bp[nt][kt][lane] (8 k-bytes each).
__global__ __launch_bounds__(256) void k_pack(
    const int* __restrict__ tok, const float* __restrict__ E,
    const float* __restrict__ Wi, const float* __restrict__ Wh,
    unsigned long long* __restrict__ Bp, float* __restrict__ h, float* __restrict__ c,
    unsigned char* __restrict__ Ahb1, float* __restrict__ Zac, float* __restrict__ Sac,
    float* __restrict__ out){
  const int tid = threadIdx.x;
  const int nb = blockIdx.x;            // 0..127
  const int kt = blockIdx.y;            // 0..71
  __shared__ unsigned char lds[32][64];
  {
    const int kl = tid >> 3;            // 0..31
    const int n0 = (tid & 7) * 8;
    const int k  = kt*32 + kl;
    const float* W = (k < EMB) ? (Wi + (size_t)k*NG) : (Wh + (size_t)(k-EMB)*NG);
    const float4 f0 = *(const float4*)(W + nb*64 + n0);
    const float4 f1 = *(const float4*)(W + nb*64 + n0 + 4);
    unsigned long long pk = 0ull;
    pk |= (unsigned long long)f2e4m3(f0.x*WSCALE);
    pk |= (unsigned long long)f2e4m3(f0.y*WSCALE) << 8;
    pk |= (unsigned long long)f2e4m3(f0.z*WSCALE) << 16;
    pk |= (unsigned long long)f2e4m3(f0.w*WSCALE) << 24;
    pk |= (unsigned long long)f2e4m3(f1.x*WSCALE) << 32;
    pk |= (unsigned long long)f2e4m3(f1.y*WSCALE) << 40;
    pk |= (unsigned long long)f2e4m3(f1.z*WSCALE) << 48;
    pk |= (unsigned long long)f2e4m3(f1.w*WSCALE) << 56;
    *(unsigned long long*)&lds[kl][n0] = pk;
  }
  __syncthreads();
  {
    const int ntl = tid >> 6, lane = tid & 63;
    const int kgrp = lane >> 4, n16 = lane & 15;
    unsigned long long pk = 0ull;
    #pragma unroll
    for (int p=0;p<8;p++)
      pk |= ((unsigned long long)lds[kgrp*8 + p][ntl*16 + n16]) << (8*p);
    Bp[((size_t)(nb*4 + ntl)*NKT + kt)*64 + lane] = pk;
  }
  // fused init
  const int i = (kt*128 + nb)*256 + tid;
  if (i < BATCH*VOCAB){ h[i] = 0.f; c[i] = 0.f; }
  if (i < BATCH*KTOT){
    int b = i / KTOT, k = i % KTOT;
    Ahb1[i] = (k < EMB) ? f2e4m3(ASCALE*E[(size_t)tok[b*TT]*EMB + k]) : (unsigned char)0;
  }
  if (i < BATCH*LAT)
    out[(size_t)((i>>7)*TT + 0)*LAT + (i&(LAT-1))] = 0.f;  // t=0: z=0 exactly
  if (i < 7*32){ Zac[i] = 0.f; Sac[i] = 0.f; }
}

// One LSTM step: 256 blocks = (mh 0..1)*128 + (jt 0..127); 256 thr = 4 waves
// = 4 gates. Wave: M=16 (batch half) x N=16 (j-tile), full K=2304.
// A staged in LDS in MFMA fragment order (coalesced global -> swizzled LDS);
// B streamed with 8-deep double-buffer. Gates -> LDS -> fused LSTM cell.
// Block (0, mh=0) finalizes the PREVIOUS step's output (t>=2).
__global__ __launch_bounds__(256) void k_step(
    const int* __restrict__ tok, const float* __restrict__ E,
    const float* __restrict__ bias, float* __restrict__ out,
    float* __restrict__ h, float* __restrict__ c,
    float* __restrict__ Zac, float* __restrict__ Sac, float* __restrict__ Eac,
    const unsigned char* __restrict__ AhbR, unsigned char* __restrict__ AhbW,
    const unsigned long long* __restrict__ Bp, int t){
  const int tid = threadIdx.x;
  const int jt = blockIdx.x & 127, mh = blockIdx.x >> 7;   // (jt,0)/(jt,1) co-XCD
  const int g = tid >> 6, lane = tid & 63;
  const int quad = lane >> 4, col = lane & 15;
  const int slot = t - 1;

  __shared__ long As[NKT*65];           // frag (kt, q*16+c) at As[kt*65 + q*16+c]
  __shared__ float gsh[4][16][16];
  __shared__ float vsh[BATCH];

  if (jt == 0 && mh == 0 && t >= 2){    // block-uniform
    if (tid < BATCH){
      float Z = Zac[(slot-1)*32 + tid], S = Sac[(slot-1)*32 + tid];
      float Ej = Eac[(slot-1)*32 + tid];
      vsh[tid] = (3.f*S + 1.5f*Ej)/Z;
    }
    __syncthreads();
    for (int i=tid; i<BATCH*LAT; i+=256)
      out[(size_t)((i>>7)*TT + (t-1))*LAT + (i&(LAT-1))] = vsh[i>>7];
  }

  // ---- stage A (16 rows x 2304 B) coalesced -> LDS fragment order ----
  #pragma unroll
  for (int it=0; it<9; it++){
    const int ch = it*256 + tid;        // 0..2303 chunks of 16B
    const int r = ch / 144, o = ch - r*144;
    const ulonglong2 v = *(const ulonglong2*)(AhbR + (size_t)(mh*16 + r)*KTOT + o*16);
    const int kt = o >> 1, qb = (o & 1)*2;
    As[kt*65 + qb*16 + r]      = (long)v.x;
    As[kt*65 + (qb+1)*16 + r]  = (long)v.y;
  }
  __syncthreads();

  // ---- full-K MFMA: B 8-deep dbuf from global, A from LDS ----
  const long* __restrict__ BpV = (const long*)Bp;
  const size_t bbase = (size_t)(g*NJT + jt)*NKT*64 + lane;
  const int aoff = quad*16 + col;
  long bb[2][8];
  #pragma unroll
  for (int i=0;i<8;i++) bb[0][i] = BpV[bbase + (size_t)i*64];
  f32x4 acc = {0,0,0,0};
  #pragma unroll
  for (int ch2=0; ch2<9; ch2++){
    const int cur = ch2 & 1, nxt = cur ^ 1;
    if (ch2 < 8){
      #pragma unroll
      for (int i=0;i<8;i++)
        bb[nxt][i] = BpV[bbase + (size_t)((ch2+1)*8 + i)*64];
    }
    #pragma unroll
    for (int i=0;i<8;i++){
      long av = As[(ch2*8 + i)*65 + aoff];
      acc = __builtin_amdgcn_mfma_f32_16x16x32_fp8_fp8(av, bb[cur][i], acc, 0,0,0);
    }
  }
  #pragma unroll
  for (int r=0;r<4;r++)
    gsh[g][quad*4 + r][col] = acc[r];
  __syncthreads();

  // ---- fused cell: thread = (b16, jj) of 16x16 ----
  const int b16 = tid >> 4, jj = tid & 15;
  const int b = mh*16 + b16;
  const int j = jt*16 + jj;
  float ip = gsh[0][b16][jj]*DQ + bias[j];
  float fp = gsh[1][b16][jj]*DQ + bias[j + VOCAB];
  float gg = gsh[2][b16][jj]*DQ + bias[j + 2*VOCAB];
  float op = gsh[3][b16][jj]*DQ + bias[j + 3*VOCAB];
  float cold = c[b*VOCAB + j];
  float cn = sigmoidf_(fp)*cold + sigmoidf_(ip)*tanhf_(gg);
  float hn = sigmoidf_(op)*tanhf_(cn);
  const bool upd = tok[b*TT + (t-1)] != 0;
  float hf = upd ? hn : h[b*VOCAB + j];
  float cf = upd ? cn : cold;
  h[b*VOCAB + j] = hf;
  c[b*VOCAB + j] = cf;
  AhbW[b*KTOT + EMB + j] = f2e4m3(ASCALE*hf);
  const int sj = tok[b*TT + t];
  float e = __expf(hf);                 // h in (-1,1): no max-pass
  if (j == sj) Eac[slot*32 + b] = e;    // unique writer
  float z = e, s = (j < sj) ? e : 0.f;
  #pragma unroll
  for (int m=1; m<16; m<<=1){ z += __shfl_xor(z, m); s += __shfl_xor(s, m); }
  if (jj == 0){
    atomicAdd(&Zac[slot*32 + b], z);
    atomicAdd(&Sac[slot*32 + b], s);
  }
  if (mh == 0 && jt < BATCH && t < TT-1)   // stage next step's x-row (b = jt)
    AhbW[jt*KTOT + tid] = f2e4m3(ASCALE*E[(size_t)tok[jt*TT + t]*EMB + tid]);
}

// Final output (t = TT-1), slot 6.
__global__ __launch_bounds__(256) void k_out(
    const float* __restrict__ Zac, const float* __restrict__ Sac,
    const float* __restrict__ Eac, float* __restrict__ out){
  const int tid = threadIdx.x;
  __shared__ float vsh[BATCH];
  if (tid < BATCH)
    vsh[tid] = (3.f*Sac[6*32+tid] + 1.5f*Eac[6*32+tid])/Zac[6*32+tid];
  __syncthreads();
  for (int i=tid; i<BATCH*LAT; i+=256)
    out[(size_t)((i>>7)*TT + (TT-1))*LAT + (i&(LAT-1))] = vsh[i>>7];
}

extern "C" void kernel_launch(void* const* d_in, const int* in_sizes, int n_in,
                              void* d_out, int out_size, void* d_ws, size_t ws_size,
                              hipStream_t stream){
  const int*   tok  = (const int*)d_in[0];
  const float* E    = (const float*)d_in[1];
  const float* Wi   = (const float*)d_in[2];
  const float* Wh   = (const float*)d_in[3];
  const float* bias = (const float*)d_in[4];
  float* out = (float*)d_out;
  float* ws  = (float*)d_ws;
  float* h   = ws + H_OFF;
  float* c   = ws + C_OFF;
  float* Zac = ws + ZAC_OFF;
  float* Sac = ws + SAC_OFF;
  float* Eac = ws + EAC_OFF;
  unsigned char* Ahb = (unsigned char*)(ws + AHB_OFF);   // 2 buffers x 73728 B
  unsigned long long* Bp = (unsigned long long*)(ws + BP_OFF);

  k_pack<<<dim3(128, NKT), 256, 0, stream>>>(tok, E, Wi, Wh, Bp, h, c,
                                             Ahb + BATCH*KTOT, Zac, Sac, out);
  for (int t = 1; t < TT; t++){
    unsigned char* AhbR = Ahb + (t & 1)*BATCH*KTOT;
    unsigned char* AhbW = Ahb + ((t & 1) ^ 1)*BATCH*KTOT;
    k_step<<<256, 256, 0, stream>>>(tok, E, bias, out, h, c, Zac, Sac, Eac,
                                    AhbR, AhbW, Bp, t);
  }
  k_out<<<1, 256, 0, stream>>>(Zac, Sac, Eac, out);
}